// Round 7
// baseline (612.676 us; speedup 1.0000x reference)
//
#include <hip/hip_runtime.h>
#include <hip/hip_bf16.h>

#define D 64
#define N_USERS 100000
#define N_ITEMS 50000
#define N_ENT   200000
#define EPS 1e-12f
#define CHUNK 4096
#define NBINP 512   // padded bin/segment-counter array size
#define CAP   8192  // max edges per bin for LDS-staged pass 2

typedef unsigned short u16;
typedef unsigned int u32;

template<int MODE> struct Cfg;
template<> struct Cfg<0> { static constexpr int SHIFT = 9; static constexpr int NSEG = N_ENT;   };
template<> struct Cfg<1> { static constexpr int SHIFT = 7; static constexpr int NSEG = N_ITEMS; };
template<> struct Cfg<2> { static constexpr int SHIFT = 8; static constexpr int NSEG = N_USERS; };
template<int MODE> constexpr int nbin_of() {
  return (Cfg<MODE>::NSEG + (1 << Cfg<MODE>::SHIFT) - 1) >> Cfg<MODE>::SHIFT;  // = 391 all modes
}

__device__ __forceinline__ float bf2f(u16 u) {
  return __uint_as_float(((unsigned)u) << 16);
}
__device__ __forceinline__ u16 f2bf(float f) {
  unsigned u = __float_as_uint(f);
  unsigned r = (u + 0x7FFFu + ((u >> 16) & 1u)) >> 16;  // RNE
  return (u16)r;
}
// lane-constant broadcast on the VALU (v_readlane), NOT the LDS pipe
__device__ __forceinline__ float bcast(float v, int k) {
  return __uint_as_float(__builtin_amdgcn_readlane(__float_as_uint(v), k));
}

// ============================ init ==========================================
__global__ __launch_bounds__(256) void init_embed(
    const float* __restrict__ ent, const float* __restrict__ usr,
    float* __restrict__ out_ent, float* __restrict__ out_usr,
    u16* __restrict__ ent_bf, u16* __restrict__ usr_bf) {
  int i = blockIdx.x * 256 + threadIdx.x;
  if (i < N_ENT * D) {
    float v = ent[i];
    out_ent[i] = v;
    ent_bf[i] = f2bf(v);
  }
  if (i < N_USERS * D) {
    float v = usr[i];
    out_usr[i] = v;
    usr_bf[i] = f2bf(v);
  }
}

// ======================= generic scan (for blockcnt) ========================
__global__ __launch_bounds__(256) void scan_block(
    const int* __restrict__ in, int* __restrict__ out,
    int* __restrict__ bsum, int n) {
  __shared__ int sm[256];
  int tid = threadIdx.x;
  int i = blockIdx.x * 256 + tid;
  int v = (i < n) ? in[i] : 0;
  sm[tid] = v;
  __syncthreads();
  for (int ofs = 1; ofs < 256; ofs <<= 1) {
    int t = (tid >= ofs) ? sm[tid - ofs] : 0;
    __syncthreads();
    sm[tid] += t;
    __syncthreads();
  }
  if (i < n) out[i] = sm[tid] - v;  // exclusive
  if (tid == 255) bsum[blockIdx.x] = sm[255];
}

__global__ __launch_bounds__(1024) void scan_top(int* __restrict__ bsum, int nb) {
  __shared__ int sm[1024];
  int tid = threadIdx.x;
  int v = (tid < nb) ? bsum[tid] : 0;
  sm[tid] = v;
  __syncthreads();
  for (int ofs = 1; ofs < 1024; ofs <<= 1) {
    int t = (tid >= ofs) ? sm[tid - ofs] : 0;
    __syncthreads();
    sm[tid] += t;
    __syncthreads();
  }
  if (tid < nb) bsum[tid] = sm[tid] - v;  // exclusive
}

__global__ __launch_bounds__(256) void scan_addv(
    int* __restrict__ out, const int* __restrict__ bsum, int n) {
  int i = blockIdx.x * 256 + threadIdx.x;
  if (i < n) out[i] += bsum[blockIdx.x];
}

// =================== pass 1: bin histogram + binned scatter =================
template<int MODE>
__global__ __launch_bounds__(256) void p1_hist(
    const int* __restrict__ keys, int n, int* __restrict__ bc, int nblk) {
  constexpr int SHIFT = Cfg<MODE>::SHIFT;
  constexpr int NBIN = nbin_of<MODE>();
  __shared__ int h[NBINP];
  int tid = threadIdx.x;
  h[tid] = 0; h[tid + 256] = 0;
  __syncthreads();
  int base = blockIdx.x * CHUNK;
  int end = min(base + CHUNK, n);
  for (int i = base + tid; i < end; i += 256)
    atomicAdd(&h[keys[i] >> SHIFT], 1);
  __syncthreads();
  for (int b = tid; b < NBIN; b += 256)
    bc[b * nblk + blockIdx.x] = h[b];
}

template<int MODE>
__global__ __launch_bounds__(256) void p1_scatter(
    const int* __restrict__ keys, const int* __restrict__ pa,
    const int* __restrict__ pb, int n, const int* __restrict__ sbc, int nblk,
    int2* __restrict__ out) {
  constexpr int SHIFT = Cfg<MODE>::SHIFT;
  constexpr int NBIN = nbin_of<MODE>();
  __shared__ int h[NBINP];
  __shared__ int cur[NBINP];
  __shared__ int bb[NBINP];
  __shared__ int2 staged[CHUNK];
  __shared__ int dstA[CHUNK];
  int tid = threadIdx.x;
  h[tid] = 0; h[tid + 256] = 0;
  __syncthreads();
  int base = blockIdx.x * CHUNK;
  int end = min(base + CHUNK, n);
  for (int i = base + tid; i < end; i += 256)
    atomicAdd(&h[keys[i] >> SHIFT], 1);
  __syncthreads();
  int o0 = h[tid], o1 = h[tid + 256];
  // inclusive Hillis-Steele over 512 (reads pre-barrier, writes post-barrier)
  for (int ofs = 1; ofs < NBINP; ofs <<= 1) {
    int v0 = (tid >= ofs) ? h[tid - ofs] : 0;
    int v1 = (tid + 256 >= ofs) ? h[tid + 256 - ofs] : 0;
    __syncthreads();
    h[tid] += v0; h[tid + 256] += v1;
    __syncthreads();
  }
  int e0 = h[tid] - o0, e1 = h[tid + 256] - o1;  // exclusive
  cur[tid] = e0; cur[tid + 256] = e1;
  if (tid < NBIN)        bb[tid] = sbc[tid * nblk + blockIdx.x] - e0;
  if (tid + 256 < NBIN)  bb[tid + 256] = sbc[(tid + 256) * nblk + blockIdx.x] - e1;
  __syncthreads();
  for (int i = base + tid; i < end; i += 256) {
    int k = keys[i];
    int bin = k >> SHIFT;
    int payload;
    if constexpr (MODE == 0) payload = pa[i] | (pb[i] << 24);
    else                     payload = pa[i];
    int lp = atomicAdd(&cur[bin], 1);
    staged[lp] = make_int2(k, payload);
    dstA[lp] = bb[bin] + lp;
  }
  __syncthreads();
  int cnt = end - base;
  for (int t = tid; t < cnt; t += 256) out[dstA[t]] = staged[t];
}

// ============ pass 2: in-bin sort -> final payload array + offsets ==========
template<int MODE>
__global__ __launch_bounds__(256) void p2_sort(
    const int2* __restrict__ binned, const int* __restrict__ sbc, int nblk,
    int n, int* __restrict__ vals, int* __restrict__ off) {
  constexpr int SHIFT = Cfg<MODE>::SHIFT;
  constexpr int NSEG = Cfg<MODE>::NSEG;
  constexpr int SEGBIN = 1 << SHIFT;
  constexpr int NBIN = nbin_of<MODE>();
  __shared__ int h[NBINP];
  __shared__ int cur[NBINP];
  __shared__ int staged[CAP];
  int tid = threadIdx.x;
  int b = blockIdx.x;
  int start = sbc[b * nblk];
  int endp = (b == NBIN - 1) ? n : sbc[(b + 1) * nblk];
  int cnt = endp - start;
  h[tid] = 0; h[tid + 256] = 0;
  __syncthreads();
  int segbase = b << SHIFT;
  for (int t = tid; t < cnt; t += 256)
    atomicAdd(&h[binned[start + t].x - segbase], 1);
  __syncthreads();
  int o0 = h[tid], o1 = h[tid + 256];
  for (int ofs = 1; ofs < NBINP; ofs <<= 1) {
    int v0 = (tid >= ofs) ? h[tid - ofs] : 0;
    int v1 = (tid + 256 >= ofs) ? h[tid + 256 - ofs] : 0;
    __syncthreads();
    h[tid] += v0; h[tid + 256] += v1;
    __syncthreads();
  }
  int e0 = h[tid] - o0, e1 = h[tid + 256] - o1;
  // segment offsets (coalesced)
  if (tid < SEGBIN && segbase + tid < NSEG) off[segbase + tid] = start + e0;
  if (tid + 256 < SEGBIN && segbase + tid + 256 < NSEG)
    off[segbase + tid + 256] = start + e1;
  if (b == NBIN - 1 && tid == 0) off[NSEG] = n;  // sentinel
  cur[tid] = e0; cur[tid + 256] = e1;
  __syncthreads();
  if (cnt <= CAP) {
    for (int t = tid; t < cnt; t += 256) {
      int2 e = binned[start + t];
      int lp = atomicAdd(&cur[e.x - segbase], 1);
      staged[lp] = e.y;
    }
    __syncthreads();
    for (int t = tid; t < cnt; t += 256) vals[start + t] = staged[t];
  } else {  // overflow fallback: correct, scattered
    for (int t = tid; t < cnt; t += 256) {
      int2 e = binned[start + t];
      int lp = atomicAdd(&cur[e.x - segbase], 1);
      vals[start + lp] = e.y;
    }
  }
}

// ============================ per-hop kernels ===============================
// 2 dims/lane (bf16x2 dword), 2 edges/wave-step: lanes 0-31 = even edge,
// lanes 32-63 = odd edge; lane's dim pair = (2*pi, 2*pi+1), pi = lane&31.
// Halves summed at the end via shfl_xor(32). Stores from lanes 0-31 only.
__global__ __launch_bounds__(256) void kg_gather(
    const u32* __restrict__ ent2, const float2* __restrict__ relw2,
    const int* __restrict__ off, const int* __restrict__ pk,
    float2* __restrict__ ea_items2, u32* __restrict__ ent_next2,
    float2* __restrict__ res2) {
  int h = blockIdx.x * 4 + (threadIdx.x >> 6);
  if (h >= N_ENT) return;
  int lane = threadIdx.x & 63;
  int pi = lane & 31, half = lane >> 5;
  int b = off[h], e = off[h + 1];
  float2 acc = {0.f, 0.f};
  for (int j0 = b; j0 < e; j0 += 64) {
    int cnt = min(64, e - j0);
    int p = (j0 + lane < e) ? pk[j0 + lane] : 0;
    int nstep = (cnt + 1) >> 1;
    int s = 0;
    for (; s + 8 <= nstep; s += 8) {
      u32 raw[8];
      float2 rw[8];
#pragma unroll
      for (int k = 0; k < 8; ++k) {
        int pos = 2 * (s + k) + half;
        int q = __shfl(p, pos);
        raw[k] = ent2[(q & 0xFFFFFF) * 32 + pi];
        rw[k] = relw2[(((unsigned)q) >> 24) * 32 + pi];
        if (pos >= cnt) raw[k] = 0u;  // odd-tail mask (products -> 0)
      }
#pragma unroll
      for (int k = 0; k < 8; ++k) {
        acc.x += bf2f((u16)(raw[k] & 0xFFFF)) * rw[k].x;
        acc.y += bf2f((u16)(raw[k] >> 16)) * rw[k].y;
      }
    }
    for (; s < nstep; ++s) {
      int pos = 2 * s + half;
      int q = __shfl(p, pos);
      u32 raw = ent2[(q & 0xFFFFFF) * 32 + pi];
      float2 rw = relw2[(((unsigned)q) >> 24) * 32 + pi];
      if (pos >= cnt) raw = 0u;
      acc.x += bf2f((u16)(raw & 0xFFFF)) * rw.x;
      acc.y += bf2f((u16)(raw >> 16)) * rw.y;
    }
  }
  // combine the two edge-halves: all lanes end with the full segment sum
  acc.x += __shfl_xor(acc.x, 32);
  acc.y += __shfl_xor(acc.y, 32);
  if (h < N_ITEMS) {
    if (half == 0) ea_items2[h * 32 + pi] = acc;  // raw f32 pairs
  } else {
    float ss = acc.x * acc.x + acc.y * acc.y;
#pragma unroll
    for (int m = 1; m < 32; m <<= 1) ss += __shfl_xor(ss, m);
    float sc = 1.f / fmaxf(sqrtf(ss), EPS);
    float2 nv = {acc.x * sc, acc.y * sc};
    if (half == 0) {
      ent_next2[h * 32 + pi] = (u32)f2bf(nv.x) | ((u32)f2bf(nv.y) << 16);
      float2 r = res2[h * 32 + pi];
      r.x += nv.x; r.y += nv.y;
      res2[h * 32 + pi] = r;
    }
  }
}

// shared 2-dims/lane segment-sum over a bf16-pair table
__device__ __forceinline__ float2 segsum2_bf(
    const int* __restrict__ il, int b, int e, int pi, int half, int lane,
    const u32* __restrict__ tab2) {
  float2 acc = {0.f, 0.f};
  for (int j0 = b; j0 < e; j0 += 64) {
    int cnt = min(64, e - j0);
    int p = (j0 + lane < e) ? il[j0 + lane] : 0;
    int nstep = (cnt + 1) >> 1;
    int s = 0;
    for (; s + 8 <= nstep; s += 8) {
      u32 raw[8];
#pragma unroll
      for (int k = 0; k < 8; ++k) {
        int pos = 2 * (s + k) + half;
        int q = __shfl(p, pos);
        raw[k] = tab2[q * 32 + pi];
        if (pos >= cnt) raw[k] = 0u;
      }
#pragma unroll
      for (int k = 0; k < 8; ++k) {
        acc.x += bf2f((u16)(raw[k] & 0xFFFF));
        acc.y += bf2f((u16)(raw[k] >> 16));
      }
    }
    for (; s < nstep; ++s) {
      int pos = 2 * s + half;
      int q = __shfl(p, pos);
      u32 raw = tab2[q * 32 + pi];
      if (pos >= cnt) raw = 0u;
      acc.x += bf2f((u16)(raw & 0xFFFF));
      acc.y += bf2f((u16)(raw >> 16));
    }
  }
  acc.x += __shfl_xor(acc.x, 32);
  acc.y += __shfl_xor(acc.y, 32);
  return acc;
}

__global__ __launch_bounds__(256) void inter_gather(
    const u32* __restrict__ usr2, const float2* __restrict__ relw2,
    const int* __restrict__ off, const int* __restrict__ vr,
    float2* __restrict__ iu2) {
  int c = blockIdx.x * 4 + (threadIdx.x >> 6);
  if (c >= N_ITEMS) return;
  int lane = threadIdx.x & 63;
  int pi = lane & 31, half = lane >> 5;
  float2 acc = segsum2_bf(vr, off[c], off[c + 1], pi, half, lane, usr2);
  if (half == 0) {
    float2 rw0 = relw2[pi];  // relw row 0
    iu2[c * 32 + pi] = make_float2(acc.x * rw0.x, acc.y * rw0.y);
  }
}

// gate GEMM: G reads on the (conflict-free) LDS path; row broadcasts via
// v_readlane (VALU). Two accumulators break the FMA dependence chain.
__global__ __launch_bounds__(256) void fuse_items(
    const float* __restrict__ ea_items, const float* __restrict__ iu,
    const float* __restrict__ g1, const float* __restrict__ g2,
    u16* __restrict__ fus_bf, u16* __restrict__ ent_next,
    float* __restrict__ res) {
  __shared__ float G1[D][D + 1];
  __shared__ float G2[D][D + 1];
  for (int i = threadIdx.x; i < D * D; i += 256) {
    G1[i >> 6][i & 63] = g1[i];
    G2[i >> 6][i & 63] = g2[i];
  }
  __syncthreads();
  int row = blockIdx.x * 4 + (threadIdx.x >> 6);
  if (row >= N_ITEMS) return;
  int lane = threadIdx.x & 63;
  int o = row * D + lane;
  float eav = ea_items[o];
  float uv = iu[o];
  float s1 = 0.f, s2 = 0.f;
#pragma unroll
  for (int k = 0; k < D; ++k) {
    s1 += bcast(eav, k) * G1[lane][k];
    s2 += bcast(uv, k) * G2[lane][k];
  }
  float s = s1 + s2;
  float gi = s > 0.f ? s : 0.2f * s;
  float fus = gi * eav + (1.f - gi) * uv;
  fus_bf[o] = f2bf(fus);  // raw fusion (user_gather input)
  float ss = fus * fus;
#pragma unroll
  for (int m = 1; m < 64; m <<= 1) ss += __shfl_xor(ss, m);
  float nv = fus / fmaxf(sqrtf(ss), EPS);
  ent_next[o] = f2bf(nv);
  res[o] += nv;
}

__global__ __launch_bounds__(256) void user_gather(
    const u32* __restrict__ fus2, const int* __restrict__ off,
    const int* __restrict__ vc, u32* __restrict__ usr2,
    float2* __restrict__ res2) {
  int u = blockIdx.x * 4 + (threadIdx.x >> 6);
  if (u >= N_USERS) return;
  int lane = threadIdx.x & 63;
  int pi = lane & 31, half = lane >> 5;
  float2 acc = segsum2_bf(vc, off[u], off[u + 1], pi, half, lane, fus2);
  float ss = acc.x * acc.x + acc.y * acc.y;
#pragma unroll
  for (int m = 1; m < 32; m <<= 1) ss += __shfl_xor(ss, m);
  float sc = 1.f / fmaxf(sqrtf(ss), EPS);
  float2 nv = {acc.x * sc, acc.y * sc};
  if (half == 0) {
    usr2[u * 32 + pi] = (u32)f2bf(nv.x) | ((u32)f2bf(nv.y) << 16);
    float2 r = res2[u * 32 + pi];
    r.x += nv.x; r.y += nv.y;
    res2[u * 32 + pi] = r;
  }
}

// ============================ sort driver ===================================
template<int MODE>
static void run_sort(const int* keys, const int* pa, const int* pb, int n,
                     int2* binned, int* vals, int* off, int* bc, int* bsum,
                     hipStream_t stream) {
  constexpr int NBIN = nbin_of<MODE>();
  int nblk = (n + CHUNK - 1) / CHUNK;
  int len = NBIN * nblk;
  p1_hist<MODE><<<nblk, 256, 0, stream>>>(keys, n, bc, nblk);
  int nbs = (len + 255) / 256;
  scan_block<<<nbs, 256, 0, stream>>>(bc, bc, bsum, len);
  scan_top<<<1, 1024, 0, stream>>>(bsum, nbs);
  scan_addv<<<nbs, 256, 0, stream>>>(bc, bsum, len);
  p1_scatter<MODE><<<nblk, 256, 0, stream>>>(keys, pa, pb, n, bc, nblk, binned);
  p2_sort<MODE><<<NBIN, 256, 0, stream>>>(binned, bc, nblk, n, vals, off);
}

// ============================ launch ========================================
extern "C" void kernel_launch(void* const* d_in, const int* in_sizes, int n_in,
                              void* d_out, int out_size, void* d_ws, size_t ws_size,
                              hipStream_t stream) {
  const float* user_emb = (const float*)d_in[0];
  const float* ent_emb  = (const float*)d_in[1];
  const float* relw     = (const float*)d_in[2];
  const float* g1       = (const float*)d_in[3];
  const float* g2       = (const float*)d_in[4];
  const int*   head     = (const int*)d_in[5];
  const int*   tail     = (const int*)d_in[6];
  const int*   etype    = (const int*)d_in[7];
  const int*   mrow     = (const int*)d_in[8];
  const int*   mcol     = (const int*)d_in[9];

  const int n_edges = in_sizes[5];
  const int n_inter = in_sizes[8];
  const int n_hops  = in_sizes[3] / (D * D);

  // ---- workspace carve ----
  u16* entA_bf = (u16*)d_ws;
  u16* entB_bf = entA_bf + (size_t)N_ENT * D;
  u16* usr_bf  = entB_bf + (size_t)N_ENT * D;
  u16* fus_bf  = usr_bf + (size_t)N_USERS * D;
  float* ea_items = (float*)(fus_bf + (size_t)N_ITEMS * D);
  float* iu       = ea_items + (size_t)N_ITEMS * D;
  int* ip = (int*)(iu + (size_t)N_ITEMS * D);
  int* o_head = ip;   ip += N_ENT + 1;
  int* o_col  = ip;   ip += N_ITEMS + 1;
  int* o_row  = ip;   ip += N_USERS + 1;
  int* pk_head = ip;  ip += n_edges;   // packed tail|etype<<24, grouped by head
  int* vr_col  = ip;  ip += n_inter;   // mrow grouped by col
  int* vc_row  = ip;  ip += n_inter;   // mcol grouped by row
  int* bc      = ip;  ip += 391 * ((n_edges + CHUNK - 1) / CHUNK) + 1;  // blockcnt (max)
  int* bsum    = ip;  ip += 1024;

  float* out_ent = (float*)d_out;
  float* out_usr = out_ent + (size_t)N_ENT * D;

  // ---- sort temps live in d_out (overwritten by init_embed afterwards) ----
  int2* bin_head = (int2*)d_out;
  int2* bin_col  = bin_head + n_edges;
  int2* bin_row  = bin_col + n_inter;

  run_sort<0>(head, tail, etype, n_edges, bin_head, pk_head, o_head, bc, bsum, stream);
  run_sort<1>(mcol, mrow, nullptr, n_inter, bin_col, vr_col, o_col, bc, bsum, stream);
  run_sort<2>(mrow, mcol, nullptr, n_inter, bin_row, vc_row, o_row, bc, bsum, stream);

  // residual init AFTER sorting (d_out was scratch until here)
  init_embed<<<(N_ENT * D + 255) / 256, 256, 0, stream>>>(
      ent_emb, user_emb, out_ent, out_usr, entA_bf, usr_bf);

  for (int i = 0; i < n_hops; ++i) {
    const u16* ecur = (i & 1) ? entB_bf : entA_bf;
    u16* enxt       = (i & 1) ? entA_bf : entB_bf;

    kg_gather<<<(N_ENT + 3) / 4, 256, 0, stream>>>(
        (const u32*)ecur, (const float2*)relw, o_head, pk_head,
        (float2*)ea_items, (u32*)enxt, (float2*)out_ent);

    inter_gather<<<(N_ITEMS + 3) / 4, 256, 0, stream>>>(
        (const u32*)usr_bf, (const float2*)relw, o_col, vr_col, (float2*)iu);

    fuse_items<<<(N_ITEMS + 3) / 4, 256, 0, stream>>>(
        ea_items, iu, g1 + (size_t)i * D * D, g2 + (size_t)i * D * D,
        fus_bf, enxt, out_ent);

    user_gather<<<(N_USERS + 3) / 4, 256, 0, stream>>>(
        (const u32*)fus_bf, o_row, vc_row, (u32*)usr_bf, (float2*)out_usr);
  }
}

// Round 8
// 588.778 us; speedup vs baseline: 1.0406x; 1.0406x over previous
//
#include <hip/hip_runtime.h>
#include <hip/hip_bf16.h>

#define D 64
#define N_USERS 100000
#define N_ITEMS 50000
#define N_ENT   200000
#define EPS 1e-12f
#define CHUNK 4096
#define NBINP 512   // padded bin/segment-counter array size
#define CAP   8192  // max edges per bin for LDS-staged pass 2

typedef unsigned short u16;
typedef unsigned int u32;
typedef unsigned long long u64;

template<int MODE> struct Cfg;
template<> struct Cfg<0> { static constexpr int SHIFT = 9; static constexpr int NSEG = N_ENT;   };
template<> struct Cfg<1> { static constexpr int SHIFT = 7; static constexpr int NSEG = N_ITEMS; };
template<> struct Cfg<2> { static constexpr int SHIFT = 8; static constexpr int NSEG = N_USERS; };
template<int MODE> constexpr int nbin_of() {
  return (Cfg<MODE>::NSEG + (1 << Cfg<MODE>::SHIFT) - 1) >> Cfg<MODE>::SHIFT;  // = 391 all modes
}

__device__ __forceinline__ float bf2f(u16 u) {
  return __uint_as_float(((unsigned)u) << 16);
}
__device__ __forceinline__ u16 f2bf(float f) {
  unsigned u = __float_as_uint(f);
  unsigned r = (u + 0x7FFFu + ((u >> 16) & 1u)) >> 16;  // RNE
  return (u16)r;
}
__device__ __forceinline__ float wave_rsqnorm(float v) {
  float ss = v * v;
#pragma unroll
  for (int m = 1; m < 64; m <<= 1) ss += __shfl_xor(ss, m);
  return 1.f / fmaxf(sqrtf(ss), EPS);
}
// lane-constant broadcast on the VALU (v_readlane), NOT the LDS pipe
__device__ __forceinline__ float bcast(float v, int k) {
  return __uint_as_float(__builtin_amdgcn_readlane(__float_as_uint(v), k));
}

// ============================ init ==========================================
__global__ __launch_bounds__(256) void init_embed(
    const float* __restrict__ ent, const float* __restrict__ usr,
    float* __restrict__ out_ent, float* __restrict__ out_usr,
    u16* __restrict__ ent_bf, u16* __restrict__ usr_bf) {
  int i = blockIdx.x * 256 + threadIdx.x;
  if (i < N_ENT * D) {
    float v = ent[i];
    out_ent[i] = v;
    ent_bf[i] = f2bf(v);
  }
  if (i < N_USERS * D) {
    float v = usr[i];
    out_usr[i] = v;
    usr_bf[i] = f2bf(v);
  }
}

// ======================= generic scan (for blockcnt) ========================
__global__ __launch_bounds__(256) void scan_block(
    const int* __restrict__ in, int* __restrict__ out,
    int* __restrict__ bsum, int n) {
  __shared__ int sm[256];
  int tid = threadIdx.x;
  int i = blockIdx.x * 256 + tid;
  int v = (i < n) ? in[i] : 0;
  sm[tid] = v;
  __syncthreads();
  for (int ofs = 1; ofs < 256; ofs <<= 1) {
    int t = (tid >= ofs) ? sm[tid - ofs] : 0;
    __syncthreads();
    sm[tid] += t;
    __syncthreads();
  }
  if (i < n) out[i] = sm[tid] - v;  // exclusive
  if (tid == 255) bsum[blockIdx.x] = sm[255];
}

__global__ __launch_bounds__(1024) void scan_top(int* __restrict__ bsum, int nb) {
  __shared__ int sm[1024];
  int tid = threadIdx.x;
  int v = (tid < nb) ? bsum[tid] : 0;
  sm[tid] = v;
  __syncthreads();
  for (int ofs = 1; ofs < 1024; ofs <<= 1) {
    int t = (tid >= ofs) ? sm[tid - ofs] : 0;
    __syncthreads();
    sm[tid] += t;
    __syncthreads();
  }
  if (tid < nb) bsum[tid] = sm[tid] - v;  // exclusive
}

__global__ __launch_bounds__(256) void scan_addv(
    int* __restrict__ out, const int* __restrict__ bsum, int n) {
  int i = blockIdx.x * 256 + threadIdx.x;
  if (i < n) out[i] += bsum[blockIdx.x];
}

// =================== pass 1: bin histogram + binned scatter =================
template<int MODE>
__global__ __launch_bounds__(256) void p1_hist(
    const int* __restrict__ keys, int n, int* __restrict__ bc, int nblk) {
  constexpr int SHIFT = Cfg<MODE>::SHIFT;
  constexpr int NBIN = nbin_of<MODE>();
  __shared__ int h[NBINP];
  int tid = threadIdx.x;
  h[tid] = 0; h[tid + 256] = 0;
  __syncthreads();
  int base = blockIdx.x * CHUNK;
  int end = min(base + CHUNK, n);
  for (int i = base + tid; i < end; i += 256)
    atomicAdd(&h[keys[i] >> SHIFT], 1);
  __syncthreads();
  for (int b = tid; b < NBIN; b += 256)
    bc[b * nblk + blockIdx.x] = h[b];
}

template<int MODE>
__global__ __launch_bounds__(256) void p1_scatter(
    const int* __restrict__ keys, const int* __restrict__ pa,
    const int* __restrict__ pb, int n, const int* __restrict__ sbc, int nblk,
    int2* __restrict__ out) {
  constexpr int SHIFT = Cfg<MODE>::SHIFT;
  constexpr int NBIN = nbin_of<MODE>();
  __shared__ int h[NBINP];
  __shared__ int cur[NBINP];
  __shared__ int bb[NBINP];
  __shared__ int2 staged[CHUNK];
  __shared__ int dstA[CHUNK];
  int tid = threadIdx.x;
  h[tid] = 0; h[tid + 256] = 0;
  __syncthreads();
  int base = blockIdx.x * CHUNK;
  int end = min(base + CHUNK, n);
  for (int i = base + tid; i < end; i += 256)
    atomicAdd(&h[keys[i] >> SHIFT], 1);
  __syncthreads();
  int o0 = h[tid], o1 = h[tid + 256];
  // inclusive Hillis-Steele over 512 (reads pre-barrier, writes post-barrier)
  for (int ofs = 1; ofs < NBINP; ofs <<= 1) {
    int v0 = (tid >= ofs) ? h[tid - ofs] : 0;
    int v1 = (tid + 256 >= ofs) ? h[tid + 256 - ofs] : 0;
    __syncthreads();
    h[tid] += v0; h[tid + 256] += v1;
    __syncthreads();
  }
  int e0 = h[tid] - o0, e1 = h[tid + 256] - o1;  // exclusive
  cur[tid] = e0; cur[tid + 256] = e1;
  if (tid < NBIN)        bb[tid] = sbc[tid * nblk + blockIdx.x] - e0;
  if (tid + 256 < NBIN)  bb[tid + 256] = sbc[(tid + 256) * nblk + blockIdx.x] - e1;
  __syncthreads();
  for (int i = base + tid; i < end; i += 256) {
    int k = keys[i];
    int bin = k >> SHIFT;
    int payload;
    if constexpr (MODE == 0) payload = pa[i] | (pb[i] << 24);
    else                     payload = pa[i];
    int lp = atomicAdd(&cur[bin], 1);
    staged[lp] = make_int2(k, payload);
    dstA[lp] = bb[bin] + lp;
  }
  __syncthreads();
  int cnt = end - base;
  for (int t = tid; t < cnt; t += 256) out[dstA[t]] = staged[t];
}

// ==== pass 2: in-bin sort -> payload array + per-edge seg id + offsets ======
template<int MODE>
__global__ __launch_bounds__(256) void p2_sort(
    const int2* __restrict__ binned, const int* __restrict__ sbc, int nblk,
    int n, int* __restrict__ vals, int* __restrict__ hids,
    int* __restrict__ off) {
  constexpr int SHIFT = Cfg<MODE>::SHIFT;
  constexpr int NSEG = Cfg<MODE>::NSEG;
  constexpr int SEGBIN = 1 << SHIFT;
  constexpr int NBIN = nbin_of<MODE>();
  __shared__ int h[NBINP];
  __shared__ int cur[NBINP];
  __shared__ int staged[CAP];
  int tid = threadIdx.x;
  int b = blockIdx.x;
  int start = sbc[b * nblk];
  int endp = (b == NBIN - 1) ? n : sbc[(b + 1) * nblk];
  int cnt = endp - start;
  h[tid] = 0; h[tid + 256] = 0;
  __syncthreads();
  int segbase = b << SHIFT;
  for (int t = tid; t < cnt; t += 256)
    atomicAdd(&h[binned[start + t].x - segbase], 1);
  __syncthreads();
  int o0 = h[tid], o1 = h[tid + 256];
  for (int ofs = 1; ofs < NBINP; ofs <<= 1) {
    int v0 = (tid >= ofs) ? h[tid - ofs] : 0;
    int v1 = (tid + 256 >= ofs) ? h[tid + 256 - ofs] : 0;
    __syncthreads();
    h[tid] += v0; h[tid + 256] += v1;
    __syncthreads();
  }
  int e0 = h[tid] - o0, e1 = h[tid + 256] - o1;
  // segment offsets (coalesced)
  if (tid < SEGBIN && segbase + tid < NSEG) off[segbase + tid] = start + e0;
  if (tid + 256 < SEGBIN && segbase + tid + 256 < NSEG)
    off[segbase + tid + 256] = start + e1;
  if (b == NBIN - 1 && tid == 0) off[NSEG] = n;  // sentinel
  cur[tid] = e0; cur[tid + 256] = e1;
  __syncthreads();
  if (cnt <= CAP) {
    for (int t = tid; t < cnt; t += 256) {
      int2 e = binned[start + t];
      int lp = atomicAdd(&cur[e.x - segbase], 1);
      staged[lp] = e.y;
      hids[start + lp] = e.x;  // small-range scatter (20KB window)
    }
    __syncthreads();
    for (int t = tid; t < cnt; t += 256) vals[start + t] = staged[t];
  } else {  // overflow fallback: correct, scattered
    for (int t = tid; t < cnt; t += 256) {
      int2 e = binned[start + t];
      int lp = atomicAdd(&cur[e.x - segbase], 1);
      vals[start + lp] = e.y;
      hids[start + lp] = e.x;
    }
  }
}

// ======================= edge-parallel gather ===============================
// One wave per 64 consecutive sorted edges (lane = dim). Loads are always
// 8-deep regardless of segment length; segment boundaries from a ballot mask.
// Interior segments -> plain row store to raw (f32, zeroed); window-spanning
// segments -> atomicAdd (~2/window).
template<bool REL>
__global__ __launch_bounds__(256) void edge_gather(
    const u16* __restrict__ tab, const float* __restrict__ relw,
    const int* __restrict__ pk, const int* __restrict__ hid,
    float* __restrict__ raw, int n) {
  __shared__ float lds_relw[REL ? 32 * D : 1];
  if (REL) {
    for (int i = threadIdx.x; i < 32 * D; i += 256) lds_relw[i] = relw[i];
    __syncthreads();
  }
  int win = blockIdx.x * 4 + (threadIdx.x >> 6);
  int S = win * 64;
  if (S >= n) return;
  int lane = threadIdx.x & 63;
  int cnt = min(64, n - S);
  int p  = (S + lane < n) ? pk[S + lane]  : 0;
  int hd = (S + lane < n) ? hid[S + lane] : -3;
  int hp = (S > 0) ? hid[S - 1] : -4;
  int hn = (S + 64 < n) ? hid[S + 64] : -5;
  int hnl = __shfl_down(hd, 1);
  if (lane == 63) hnl = hn;
  u64 real = __ballot(hd != hnl);
  if (cnt < 64) real &= (1ull << cnt) - 1ull;
  u64 emit = real | (1ull << (cnt - 1));  // always emit at window end
  bool start_in = (__shfl(hd, 0) != hp);
  float acc = 0.f;
  if (cnt == 64) {
    for (int base = 0; base < 64; base += 8) {
      u16 r[8]; int et[8];
#pragma unroll
      for (int k = 0; k < 8; ++k) {
        int q = __shfl(p, base + k);
        if (REL) {
          r[k] = tab[(size_t)(q & 0xFFFFFF) * D + lane];
          et[k] = ((unsigned)q) >> 24;
        } else {
          r[k] = tab[(size_t)q * D + lane];
        }
      }
#pragma unroll
      for (int k = 0; k < 8; ++k) {
        int j = base + k;
        float c = bf2f(r[k]);
        if (REL) c *= lds_relw[et[k] * D + lane];
        acc += c;
        if ((emit >> j) & 1ull) {
          int h = __shfl(hd, j);
          float* dst = raw + (size_t)h * D + lane;
          if (start_in && ((real >> j) & 1ull)) *dst = acc;
          else atomicAdd(dst, acc);
          acc = 0.f;
          start_in = true;
        }
      }
    }
  } else {  // partial tail window (not hit for n % 64 == 0)
    for (int j = 0; j < cnt; ++j) {
      int q = __shfl(p, j);
      float c;
      if (REL) c = bf2f(tab[(size_t)(q & 0xFFFFFF) * D + lane]) *
                   lds_relw[(((unsigned)q) >> 24) * D + lane];
      else     c = bf2f(tab[(size_t)q * D + lane]);
      acc += c;
      if ((emit >> j) & 1ull) {
        int h = __shfl(hd, j);
        float* dst = raw + (size_t)h * D + lane;
        if (start_in && ((real >> j) & 1ull)) *dst = acc;
        else atomicAdd(dst, acc);
        acc = 0.f;
        start_in = true;
      }
    }
  }
}

// ===================== finalize: normalize + residual =======================
__global__ __launch_bounds__(256) void fin_rows(
    const float* __restrict__ raw, u16* __restrict__ out_bf,
    float* __restrict__ res, int row0, int nrows) {
  int r = blockIdx.x * 4 + (threadIdx.x >> 6);
  if (r >= nrows) return;
  int row = row0 + r;
  int lane = threadIdx.x & 63;
  size_t o = (size_t)row * D + lane;
  float v = raw[o];
  float nv = v * wave_rsqnorm(v);
  out_bf[o] = f2bf(nv);
  res[o] += nv;
}

// =================== gate GEMM + fusion (items) =============================
// ea = raw entity agg (f32), uv = raw user-sum * relw[0]. Row broadcasts via
// v_readlane (VALU); G reads on conflict-free LDS.
__global__ __launch_bounds__(256) void fuse_items(
    const float* __restrict__ ent_raw, const float* __restrict__ iu,
    const float* __restrict__ relw,
    const float* __restrict__ g1, const float* __restrict__ g2,
    u16* __restrict__ fus_bf, u16* __restrict__ ent_bf,
    float* __restrict__ res) {
  __shared__ float G1[D][D + 1];
  __shared__ float G2[D][D + 1];
  for (int i = threadIdx.x; i < D * D; i += 256) {
    G1[i >> 6][i & 63] = g1[i];
    G2[i >> 6][i & 63] = g2[i];
  }
  __syncthreads();
  int row = blockIdx.x * 4 + (threadIdx.x >> 6);
  if (row >= N_ITEMS) return;
  int lane = threadIdx.x & 63;
  size_t o = (size_t)row * D + lane;
  float eav = ent_raw[o];
  float uv = iu[o] * relw[lane];  // apply relw[0] here (factored out)
  float s1 = 0.f, s2 = 0.f;
#pragma unroll
  for (int k = 0; k < D; ++k) {
    s1 += bcast(eav, k) * G1[lane][k];
    s2 += bcast(uv, k) * G2[lane][k];
  }
  float s = s1 + s2;
  float gi = s > 0.f ? s : 0.2f * s;
  float fus = gi * eav + (1.f - gi) * uv;
  fus_bf[o] = f2bf(fus);  // raw fusion (user gather input)
  float nv = fus * wave_rsqnorm(fus);
  ent_bf[o] = f2bf(nv);   // normalized item row (next-hop entity table)
  res[o] += nv;
}

// ============================ sort driver ===================================
template<int MODE>
static void run_sort(const int* keys, const int* pa, const int* pb, int n,
                     int2* binned, int* vals, int* hids, int* off, int* bc,
                     int* bsum, hipStream_t stream) {
  constexpr int NBIN = nbin_of<MODE>();
  int nblk = (n + CHUNK - 1) / CHUNK;
  int len = NBIN * nblk;
  p1_hist<MODE><<<nblk, 256, 0, stream>>>(keys, n, bc, nblk);
  int nbs = (len + 255) / 256;
  scan_block<<<nbs, 256, 0, stream>>>(bc, bc, bsum, len);
  scan_top<<<1, 1024, 0, stream>>>(bsum, nbs);
  scan_addv<<<nbs, 256, 0, stream>>>(bc, bsum, len);
  p1_scatter<MODE><<<nblk, 256, 0, stream>>>(keys, pa, pb, n, bc, nblk, binned);
  p2_sort<MODE><<<NBIN, 256, 0, stream>>>(binned, bc, nblk, n, vals, hids, off);
}

// ============================ launch ========================================
extern "C" void kernel_launch(void* const* d_in, const int* in_sizes, int n_in,
                              void* d_out, int out_size, void* d_ws, size_t ws_size,
                              hipStream_t stream) {
  const float* user_emb = (const float*)d_in[0];
  const float* ent_emb  = (const float*)d_in[1];
  const float* relw     = (const float*)d_in[2];
  const float* g1       = (const float*)d_in[3];
  const float* g2       = (const float*)d_in[4];
  const int*   head     = (const int*)d_in[5];
  const int*   tail     = (const int*)d_in[6];
  const int*   etype    = (const int*)d_in[7];
  const int*   mrow     = (const int*)d_in[8];
  const int*   mcol     = (const int*)d_in[9];

  const int n_edges = in_sizes[5];
  const int n_inter = in_sizes[8];
  const int n_hops  = in_sizes[3] / (D * D);

  // ---- workspace carve ----
  u16* ent_bf = (u16*)d_ws;                       // 25.6 MB (single buffer,
  u16* usr_bf = ent_bf + (size_t)N_ENT * D;       //  updated in place per hop)
  u16* fus_bf = usr_bf + (size_t)N_USERS * D;
  float* ent_raw = (float*)(fus_bf + (size_t)N_ITEMS * D);  // 51.2 MB
  float* usr_raw = ent_raw + (size_t)N_ENT * D;             // 25.6 MB
  float* iu      = usr_raw;                       // aliases first 12.8 MB
  int* ip = (int*)(usr_raw + (size_t)N_USERS * D);
  int* o_head = ip;   ip += N_ENT + 1;
  int* o_col  = ip;   ip += N_ITEMS + 1;
  int* o_row  = ip;   ip += N_USERS + 1;
  int* pk_head = ip;  ip += n_edges;   // packed tail|etype<<24, grouped by head
  int* hid_h   = ip;  ip += n_edges;   // head id per sorted edge
  int* vr_col  = ip;  ip += n_inter;   // mrow grouped by col
  int* hid_c   = ip;  ip += n_inter;   // col id per sorted interaction
  int* vc_row  = ip;  ip += n_inter;   // mcol grouped by row
  int* hid_r   = ip;  ip += n_inter;   // row id per sorted interaction
  int* bc      = ip;  ip += 391 * ((n_edges + CHUNK - 1) / CHUNK) + 64;
  int* bsum    = ip;  ip += 1024;

  float* out_ent = (float*)d_out;
  float* out_usr = out_ent + (size_t)N_ENT * D;

  // ---- sort temps live in d_out (overwritten by init_embed afterwards) ----
  int2* bin_head = (int2*)d_out;
  int2* bin_col  = bin_head + n_edges;
  int2* bin_row  = bin_col + n_inter;

  run_sort<0>(head, tail, etype, n_edges, bin_head, pk_head, hid_h, o_head,
              bc, bsum, stream);
  run_sort<1>(mcol, mrow, nullptr, n_inter, bin_col, vr_col, hid_c, o_col,
              bc, bsum, stream);
  run_sort<2>(mrow, mcol, nullptr, n_inter, bin_row, vc_row, hid_r, o_row,
              bc, bsum, stream);

  // residual init AFTER sorting (d_out was scratch until here)
  init_embed<<<(N_ENT * D + 255) / 256, 256, 0, stream>>>(
      ent_emb, user_emb, out_ent, out_usr, ent_bf, usr_bf);

  const int nwin_kg = (n_edges + 63) / 64;
  const int nwin_in = (n_inter + 63) / 64;

  for (int i = 0; i < n_hops; ++i) {
    // zero raw accumulators (targets of boundary atomics)
    hipMemsetAsync(ent_raw, 0, (size_t)N_ENT * D * sizeof(float), stream);
    hipMemsetAsync(iu, 0, (size_t)N_ITEMS * D * sizeof(float), stream);

    // KG aggregate: raw f32 per head
    edge_gather<true><<<(nwin_kg + 3) / 4, 256, 0, stream>>>(
        ent_bf, relw, pk_head, hid_h, ent_raw, n_edges);

    // item<-user aggregate: raw f32 (relw0 applied in fuse)
    edge_gather<false><<<(nwin_in + 3) / 4, 256, 0, stream>>>(
        usr_bf, nullptr, vr_col, hid_c, iu, n_inter);

    // gate + fusion on items (reads raw ent + raw iu)
    fuse_items<<<(N_ITEMS + 3) / 4, 256, 0, stream>>>(
        ent_raw, iu, relw, g1 + (size_t)i * D * D, g2 + (size_t)i * D * D,
        fus_bf, ent_bf, out_ent);

    // normalize non-item entity rows + residual
    fin_rows<<<(N_ENT - N_ITEMS + 3) / 4, 256, 0, stream>>>(
        ent_raw, ent_bf, out_ent, N_ITEMS, N_ENT - N_ITEMS);

    // user aggregate over raw fusion rows (zero AFTER fuse consumed iu alias)
    hipMemsetAsync(usr_raw, 0, (size_t)N_USERS * D * sizeof(float), stream);
    edge_gather<false><<<(nwin_in + 3) / 4, 256, 0, stream>>>(
        fus_bf, nullptr, vc_row, hid_r, usr_raw, n_inter);

    // normalize users + residual
    fin_rows<<<(N_USERS + 3) / 4, 256, 0, stream>>>(
        usr_raw, usr_bf, out_usr, 0, N_USERS);
  }
}